// Round 1
// baseline (442.637 us; speedup 1.0000x reference)
//
#include <hip/hip_runtime.h>
#include <stdint.h>

// Fused LoRA linear: out[m,o] = bias[o] + 2 * sum_r (sum_i x[m,i]*A[r,i]) * B[o,r]
// x: [8192, 4096] f32, A: [16, 4096] f32, B: [4096, 16] f32, bias: [4096] f32
//
// Single kernel: each block owns 8 token rows. Phase A computes t[8][16] =
// 2*(x_rows @ A^T) exactly as the previous lora_phase1 (verified structure:
// A chunk double-buffered in LDS via global_load_lds width=16, x on the
// vmcnt prefetch path, butterfly reduce), but lands t in LDS instead of
// global. Phase B then streams the block's own 8x4096 output slice.
// This removes the second launch, the inter-kernel drain (phase2 could not
// start until the LAST phase1 block retired), and the t global round-trip.
// x loads and out stores are nontemporal so 268 MB of single-use streaming
// traffic stops evicting the hot A/B panels (512 KB) from L2.

constexpr int IN_F  = 4096;
constexpr int OUT_F = 4096;
constexpr int RANK  = 16;
constexpr int M_TOT = 4 * 2048;           // 8192 token rows
constexpr float SCALING = 2.0f;           // ALPHA / R

typedef const __attribute__((address_space(1))) void* as1_cvp;
typedef __attribute__((address_space(3))) void*       as3_vp;
typedef float f32x4 __attribute__((ext_vector_type(4)));

__global__ __launch_bounds__(256, 4) void lora_fused(
    const float* __restrict__ x, const float* __restrict__ A,
    const float* __restrict__ B, const float* __restrict__ bias,
    float* __restrict__ out)
{
    __shared__ float4 As[2][RANK][64];    // 2 x 16 KB double-buffered A chunk
    __shared__ float  t_lds[8][RANK];     // block-local t tile (512 B)

    const int lane = threadIdx.x & 63;
    const int wave = threadIdx.x >> 6;
    const int mblk = blockIdx.x * 8;      // first token row of this block
    const int row0 = mblk + wave * 2;     // this wave's 2 rows

    const float4* __restrict__ A4 = (const float4*)A;
    const f32x4*  __restrict__ x0 = (const f32x4*)(x + (size_t)row0 * IN_F);
    const f32x4*  __restrict__ x1 = (const f32x4*)(x + (size_t)(row0 + 1) * IN_F);

    // ---------------- Phase A: t = 2 * (x_rows @ A^T) ----------------
    float acc0[RANK], acc1[RANK];
#pragma unroll
    for (int r = 0; r < RANK; ++r) { acc0[r] = 0.0f; acc1[r] = 0.0f; }

    // Stage j=0 into buf 0; prefetch x chunk 0 (nontemporal: read-once stream).
#pragma unroll
    for (int rr = 0; rr < 4; ++rr) {
        const int r = wave * 4 + rr;
        __builtin_amdgcn_global_load_lds((as1_cvp)(A4 + (size_t)r * (IN_F / 4) + lane),
                                         (as3_vp)(&As[0][r][0]), 16, 0, 0);
    }
    f32x4 xc0 = __builtin_nontemporal_load(x0 + lane);
    f32x4 xc1 = __builtin_nontemporal_load(x1 + lane);
    __syncthreads();

    int buf = 0;
#pragma unroll 1
    for (int j = 0; j < 16; ++j) {
        f32x4 xn0, xn1;
        if (j < 15) {
            const int c4 = (j + 1) * 64 + lane;
#pragma unroll
            for (int rr = 0; rr < 4; ++rr) {
                const int r = wave * 4 + rr;
                __builtin_amdgcn_global_load_lds(
                    (as1_cvp)(A4 + (size_t)r * (IN_F / 4) + c4),
                    (as3_vp)(&As[buf ^ 1][r][0]), 16, 0, 0);
            }
            xn0 = __builtin_nontemporal_load(x0 + c4);
            xn1 = __builtin_nontemporal_load(x1 + c4);
        }

#pragma unroll
        for (int r = 0; r < RANK; ++r) {
            const float4 av = As[buf][r][lane];   // ds_read_b128
            acc0[r] += xc0.x * av.x;
            acc0[r] += xc0.y * av.y;
            acc0[r] += xc0.z * av.z;
            acc0[r] += xc0.w * av.w;
            acc1[r] += xc1.x * av.x;
            acc1[r] += xc1.y * av.y;
            acc1[r] += xc1.z * av.z;
            acc1[r] += xc1.w * av.w;
        }

        if (j < 15) {
            __syncthreads();   // all waves done reading As[buf]; staging drained
            buf ^= 1;
            xc0 = xn0;
            xc1 = xn1;
        }
    }

    // Cross-lane butterfly reduce (64 lanes) for each of the 2x16 sums;
    // land t in LDS (block-local) instead of global.
#pragma unroll
    for (int p = 0; p < 2; ++p) {
        float out_v = 0.0f;
#pragma unroll
        for (int r = 0; r < RANK; ++r) {
            float v = (p == 0) ? acc0[r] : acc1[r];
#pragma unroll
            for (int s = 1; s < 64; s <<= 1)
                v += __shfl_xor(v, s, 64);
            out_v = (lane == r) ? v : out_v;
        }
        if (lane < RANK)
            t_lds[wave * 2 + p][lane] = SCALING * out_v;
    }
    __syncthreads();

    // ---------------- Phase B: out_rows = t @ B^T + bias ----------------
    // 4 column-chunks of 1024; thread owns 4 cols per chunk, all 8 rows.
    const float4* __restrict__ B4 = (const float4*)B;
#pragma unroll 1
    for (int c = 0; c < 4; ++c) {
        const int o0 = c * 1024 + threadIdx.x * 4;   // first owned column

        // b[q][rr] = B[o0+q][4*rr .. 4*rr+3]  (L2-resident after first pass)
        float4 b[4][4];
#pragma unroll
        for (int q = 0; q < 4; ++q)
#pragma unroll
            for (int rr = 0; rr < 4; ++rr)
                b[q][rr] = B4[(size_t)(o0 + q) * 4 + rr];

        const float4 bs = *(const float4*)(bias + o0);

#pragma unroll
        for (int mi = 0; mi < 8; ++mi) {
            // broadcast reads (same address across wave -> conflict-free)
            const float4 tv0 = *(const float4*)&t_lds[mi][0];
            const float4 tv1 = *(const float4*)&t_lds[mi][4];
            const float4 tv2 = *(const float4*)&t_lds[mi][8];
            const float4 tv3 = *(const float4*)&t_lds[mi][12];
            const float4 tv[4] = {tv0, tv1, tv2, tv3};

            float v[4] = {bs.x, bs.y, bs.z, bs.w};
#pragma unroll
            for (int q = 0; q < 4; ++q) {
#pragma unroll
                for (int rr = 0; rr < 4; ++rr) {
                    v[q] += b[q][rr].x * tv[rr].x;
                    v[q] += b[q][rr].y * tv[rr].y;
                    v[q] += b[q][rr].z * tv[rr].z;
                    v[q] += b[q][rr].w * tv[rr].w;
                }
            }
            f32x4 o4 = {v[0], v[1], v[2], v[3]};
            __builtin_nontemporal_store(
                o4, (f32x4*)(out + (size_t)(mblk + mi) * OUT_F + o0));
        }
    }
}

extern "C" void kernel_launch(void* const* d_in, const int* in_sizes, int n_in,
                              void* d_out, int out_size, void* d_ws, size_t ws_size,
                              hipStream_t stream) {
    const float* x    = (const float*)d_in[0];  // [8192, 4096]
    const float* A    = (const float*)d_in[1];  // [16, 4096]
    const float* B    = (const float*)d_in[2];  // [4096, 16]
    const float* bias = (const float*)d_in[3];  // [4096]
    float* out = (float*)d_out;                 // [8192, 4096]
    (void)d_ws; (void)ws_size;                  // t never leaves LDS now

    lora_fused<<<dim3(M_TOT / 8), dim3(256), 0, stream>>>(x, A, B, bias, out);
}